// Round 4
// baseline (119.826 us; speedup 1.0000x reference)
//
#include <hip/hip_runtime.h>
#include <math.h>

// FeatureSqueezer: quantize trunc(x*scale)/scale + 3x3 median, reflect pad=1.
// x: (16, 1024, 1024) fp32. HBM floor: 128 MB -> ~20 us @ 6.3 TB/s.
//
// No LDS: each thread owns 4 output cols (aligned float4) and keeps a 3-row
// register rolling window. Horizontal halo = 2 overlapping scalar global
// loads (same cache lines as neighbors' float4 -> L1/L2 hits, no extra HBM).
// Reflect padding folded into address math (no divergence, no extra loads):
//   left  col 4t-1: t==0 -> reflect(-1)=1  => cl = |4t-1|
//   right col 4t+4: t==255 -> reflect(1024)=1022
// Median: column triples via v_min3/v_med3/v_max3 (3 instr), merge via
//   med3(max3(lows), med3(mids), min3(highs)) (4 instr/px).

constexpr int H = 1024;
constexpr int W = 1024;
constexpr int TY = 8;   // output rows per block -> grid (128, 16) = 2048 blocks = 8/CU

__device__ __forceinline__ float min3f(float a, float b, float c) { return fminf(a, fminf(b, c)); }
__device__ __forceinline__ float max3f(float a, float b, float c) { return fmaxf(a, fmaxf(b, c)); }
__device__ __forceinline__ float med3f(float a, float b, float c) { return __builtin_amdgcn_fmed3f(a, b, c); }

__global__ __launch_bounds__(256) void fsq_kernel(const float* __restrict__ x,
                                                  const int* __restrict__ bdp,
                                                  float* __restrict__ out) {
    const int t  = threadIdx.x;            // 0..255 -> output cols 4t..4t+3
    const int y0 = blockIdx.x * TY;
    const int b  = blockIdx.y;

    const float q     = (float)((1 << bdp[0]) - 1);
    const float scale = 255.0f / q;
    const float rinv  = q / 255.0f;        // ~1/scale; quant error << 1.98e-2 threshold

    const size_t base = (size_t)b * H * W;
    const float* __restrict__ xb = x + base;
    float* __restrict__ ob       = out + base;

    const int c0 = 4 * t;
    const int cl = (c0 == 0) ? 1 : (c0 - 1);                       // reflect(-1)=1
    const int cr = (c0 + 4 < W) ? (c0 + 4) : (2 * W - 2 - W);      // reflect(1024)=1022

    float r0[6], r1[6], r2[6];

    auto loadrow = [&](int gy, float* vv) {
        gy = (gy < 0) ? 1 : ((gy >= H) ? 2 * H - 2 - gy : gy);     // reflect pad=1
        const float* row = xb + (size_t)gy * W;
        const float4 m = *(const float4*)(row + c0);               // global_load_dwordx4
        const float l = row[cl];                                   // overlapping dword (L1 hit)
        const float r = row[cr];
        vv[0] = truncf(l   * scale) * rinv;
        vv[1] = truncf(m.x * scale) * rinv;
        vv[2] = truncf(m.y * scale) * rinv;
        vv[3] = truncf(m.z * scale) * rinv;
        vv[4] = truncf(m.w * scale) * rinv;
        vv[5] = truncf(r   * scale) * rinv;
    };

    loadrow(y0 - 1, r0);
    loadrow(y0,     r1);

    #pragma unroll
    for (int i = 0; i < TY; ++i) {
        loadrow(y0 + 1 + i, r2);

        // sort 6 vertical triples: (min3, med3, max3)
        float lo[6], mi[6], hi[6];
        #pragma unroll
        for (int c = 0; c < 6; ++c) {
            lo[c] = min3f(r0[c], r1[c], r2[c]);
            mi[c] = med3f(r0[c], r1[c], r2[c]);
            hi[c] = max3f(r0[c], r1[c], r2[c]);
        }

        float4 o;
        o.x = med3f(max3f(lo[0], lo[1], lo[2]), med3f(mi[0], mi[1], mi[2]), min3f(hi[0], hi[1], hi[2]));
        o.y = med3f(max3f(lo[1], lo[2], lo[3]), med3f(mi[1], mi[2], mi[3]), min3f(hi[1], hi[2], hi[3]));
        o.z = med3f(max3f(lo[2], lo[3], lo[4]), med3f(mi[2], mi[3], mi[4]), min3f(hi[2], hi[3], hi[4]));
        o.w = med3f(max3f(lo[3], lo[4], lo[5]), med3f(mi[3], mi[4], mi[5]), min3f(hi[3], hi[4], hi[5]));
        *(float4*)(ob + (size_t)(y0 + i) * W + c0) = o;            // global_store_dwordx4

        #pragma unroll
        for (int c = 0; c < 6; ++c) { r0[c] = r1[c]; r1[c] = r2[c]; }  // register rename, elided
    }
}

extern "C" void kernel_launch(void* const* d_in, const int* in_sizes, int n_in,
                              void* d_out, int out_size, void* d_ws, size_t ws_size,
                              hipStream_t stream) {
    const float* x  = (const float*)d_in[0];
    const int*   bd = (const int*)d_in[1];
    float*       out = (float*)d_out;

    const int B = in_sizes[0] / (H * W);   // 16
    dim3 grid(H / TY, B);                  // (128, 16)
    fsq_kernel<<<grid, 256, 0, stream>>>(x, bd, out);
}

// Round 5
// 116.847 us; speedup vs baseline: 1.0255x; 1.0255x over previous
//
#include <hip/hip_runtime.h>
#include <math.h>

// FeatureSqueezer: quantize trunc(x*scale)/scale + 3x3 median, reflect pad=1.
// x: (16, 1024, 1024) fp32. HBM floor: 128 MB -> ~21 us @ 6.3 TB/s.
//
// Register rolling window, no LDS, no barriers. Each thread owns 4 cols
// (aligned float4). Horizontal halo via cross-lane shuffle of QUANTIZED
// values: left = shfl_up(q.w), right = shfl_down(q.x) -- 2 ds_bpermute/row
// instead of two 16B-stride scalar gathers (R4's mistake: 16 L1 transactions
// per halo instruction). Wave-edge lanes (0,63) fetch their halo with ONE
// exec-masked dword load per row. Reflect padding folded into address math.
// Median: column triples via v_min3/v_med3/v_max3, merge via
//   med3( max3(lows), med3(mids), min3(highs) ).

constexpr int H = 1024;
constexpr int W = 1024;
constexpr int TY = 8;   // output rows per block -> grid (128,16) = 2048 blocks

__device__ __forceinline__ float min3f(float a, float b, float c) { return fminf(a, fminf(b, c)); }
__device__ __forceinline__ float max3f(float a, float b, float c) { return fmaxf(a, fmaxf(b, c)); }
__device__ __forceinline__ float med3f(float a, float b, float c) { return __builtin_amdgcn_fmed3f(a, b, c); }

__global__ __launch_bounds__(256) void fsq_kernel(const float* __restrict__ x,
                                                  const int* __restrict__ bdp,
                                                  float* __restrict__ out) {
    const int t    = threadIdx.x;          // 0..255 -> output cols 4t..4t+3
    const int lane = t & 63;
    const int y0   = blockIdx.x * TY;
    const int b    = blockIdx.y;

    const float q     = (float)((1 << bdp[0]) - 1);
    const float scale = 255.0f / q;
    const float rinv  = q / 255.0f;        // ~1/scale; quant error << 1.98e-2 threshold

    const size_t base = (size_t)b * H * W;
    const float* __restrict__ xb = x + base;
    float* __restrict__ ob       = out + base;

    const int c0 = 4 * t;
    // halo column this wave-edge lane must fetch itself (with reflect):
    //   lane 0  -> col c0-1 (reflect(-1)=1 when c0==0)
    //   lane 63 -> col c0+4 (reflect(1024)=1022 when c0+4==W)
    const int cEdge = (lane == 0) ? ((c0 == 0) ? 1 : c0 - 1)
                                  : ((c0 + 4 < W) ? c0 + 4 : W - 2);
    const bool isEdge = (lane == 0) | (lane == 63);

    float r0[6], r1[6], r2[6];

    auto loadrow = [&](int gy, float* vv) {
        gy = (gy < 0) ? 1 : ((gy >= H) ? 2 * H - 2 - gy : gy);     // reflect pad=1
        const float* row = xb + (size_t)gy * W;
        const float4 m = *(const float4*)(row + c0);               // global_load_dwordx4

        float e = 0.0f;
        if (isEdge) e = row[cEdge];                                // exec-masked dword (2 lanes)

        const float q1 = truncf(m.x * scale) * rinv;
        const float q2 = truncf(m.y * scale) * rinv;
        const float q3 = truncf(m.z * scale) * rinv;
        const float q4 = truncf(m.w * scale) * rinv;
        const float qe = truncf(e   * scale) * rinv;

        float l = __shfl_up(q4, 1, 64);                            // lane-1's col 4t-1
        float r = __shfl_down(q1, 1, 64);                          // lane+1's col 4t+4
        if (lane == 0)  l = qe;
        if (lane == 63) r = qe;

        vv[0] = l; vv[1] = q1; vv[2] = q2; vv[3] = q3; vv[4] = q4; vv[5] = r;
    };

    loadrow(y0 - 1, r0);
    loadrow(y0,     r1);

    #pragma unroll
    for (int i = 0; i < TY; ++i) {
        loadrow(y0 + 1 + i, r2);

        // sort 6 vertical triples: (v_min3, v_med3, v_max3)
        float lo[6], mi[6], hi[6];
        #pragma unroll
        for (int c = 0; c < 6; ++c) {
            lo[c] = min3f(r0[c], r1[c], r2[c]);
            mi[c] = med3f(r0[c], r1[c], r2[c]);
            hi[c] = max3f(r0[c], r1[c], r2[c]);
        }

        float4 o;
        o.x = med3f(max3f(lo[0], lo[1], lo[2]), med3f(mi[0], mi[1], mi[2]), min3f(hi[0], hi[1], hi[2]));
        o.y = med3f(max3f(lo[1], lo[2], lo[3]), med3f(mi[1], mi[2], mi[3]), min3f(hi[1], hi[2], hi[3]));
        o.z = med3f(max3f(lo[2], lo[3], lo[4]), med3f(mi[2], mi[3], mi[4]), min3f(hi[2], hi[3], hi[4]));
        o.w = med3f(max3f(lo[3], lo[4], lo[5]), med3f(mi[3], mi[4], mi[5]), min3f(hi[3], hi[4], hi[5]));
        *(float4*)(ob + (size_t)(y0 + i) * W + c0) = o;            // global_store_dwordx4

        #pragma unroll
        for (int c = 0; c < 6; ++c) { r0[c] = r1[c]; r1[c] = r2[c]; }  // renamed by unroll
    }
}

extern "C" void kernel_launch(void* const* d_in, const int* in_sizes, int n_in,
                              void* d_out, int out_size, void* d_ws, size_t ws_size,
                              hipStream_t stream) {
    const float* x  = (const float*)d_in[0];
    const int*   bd = (const int*)d_in[1];
    float*       out = (float*)d_out;

    const int B = in_sizes[0] / (H * W);   // 16
    dim3 grid(H / TY, B);                  // (128, 16)
    fsq_kernel<<<grid, 256, 0, stream>>>(x, bd, out);
}

// Round 6
// 112.187 us; speedup vs baseline: 1.0681x; 1.0415x over previous
//
#include <hip/hip_runtime.h>
#include <math.h>

// FeatureSqueezer: quantize trunc(x*scale)/scale + 3x3 median, reflect pad=1.
// x: (16, 1024, 1024) fp32. HBM floor: 128 MB -> ~21 us @ 6.3 TB/s.
//
// Key round-6 changes vs round-5:
//  1) Batch-prefetch ALL 10 rows (raw dwordx4 + exec-masked edge dword) before
//     any compute -> 10-20 outstanding vmem per wave (was ~1-2: per-row
//     load->wait->compute chain was latency-bound at 4 TB/s).
//  2) Median BEFORE quantize: trunc(x*s)/s is monotone non-decreasing and
//     median is an order statistic, so median(f(x)) = f(median(x)).
//     Shuffles/median run on raw values (no VALU between vmcnt and ds_bpermute);
//     quantize once per OUTPUT pixel.
// Median: column triples via v_min3/v_med3/v_max3, merge via
//   med3( max3(lows), med3(mids), min3(highs) ).

constexpr int H = 1024;
constexpr int W = 1024;
constexpr int TY = 8;            // output rows per block
constexpr int NR = TY + 2;       // prefetched rows

__device__ __forceinline__ float min3f(float a, float b, float c) { return fminf(a, fminf(b, c)); }
__device__ __forceinline__ float max3f(float a, float b, float c) { return fmaxf(a, fmaxf(b, c)); }
__device__ __forceinline__ float med3f(float a, float b, float c) { return __builtin_amdgcn_fmed3f(a, b, c); }

__global__ __launch_bounds__(256) void fsq_kernel(const float* __restrict__ x,
                                                  const int* __restrict__ bdp,
                                                  float* __restrict__ out) {
    const int t    = threadIdx.x;          // 0..255 -> output cols 4t..4t+3
    const int lane = t & 63;
    const int y0   = blockIdx.x * TY;
    const int b    = blockIdx.y;

    const float q     = (float)((1 << bdp[0]) - 1);
    const float scale = 255.0f / q;
    const float rinv  = q / 255.0f;        // ~1/scale; quant error << 1.98e-2 threshold

    const size_t base = (size_t)b * H * W;
    const float* __restrict__ xb = x + base;
    float* __restrict__ ob       = out + base;

    const int c0 = 4 * t;
    // halo column wave-edge lanes fetch themselves (reflect folded in):
    const int cEdge = (lane == 0) ? ((c0 == 0) ? 1 : c0 - 1)
                                  : ((c0 + 4 < W) ? c0 + 4 : W - 2);
    const bool isEdge = (lane == 0) | (lane == 63);

    // ---- phase 1: issue ALL loads (raw), maximal MLP ----
    float4 m[NR];
    float  e[NR];
    #pragma unroll
    for (int r = 0; r < NR; ++r) {
        int gy = y0 - 1 + r;
        gy = (gy < 0) ? 1 : ((gy >= H) ? 2 * H - 2 - gy : gy);     // reflect pad=1
        const float* row = xb + (size_t)gy * W;
        m[r] = *(const float4*)(row + c0);                         // global_load_dwordx4
        e[r] = 0.0f;
        if (isEdge) e[r] = row[cEdge];                             // exec-masked dword
    }

    // ---- phase 2: shuffle raw halos, rolling 3-row median, quantize last ----
    float r0[6], r1[6], r2[6];

    auto mkrow = [&](int r, float* vv) {
        float l  = __shfl_up(m[r].w, 1, 64);                       // lane-1's col 4t-1
        float rr = __shfl_down(m[r].x, 1, 64);                     // lane+1's col 4t+4
        if (lane == 0)  l  = e[r];
        if (lane == 63) rr = e[r];
        vv[0] = l; vv[1] = m[r].x; vv[2] = m[r].y; vv[3] = m[r].z; vv[4] = m[r].w; vv[5] = rr;
    };

    mkrow(0, r0);
    mkrow(1, r1);

    #pragma unroll
    for (int i = 0; i < TY; ++i) {
        mkrow(2 + i, r2);

        // sort 6 vertical triples: (v_min3, v_med3, v_max3) on RAW values
        float lo[6], mi[6], hi[6];
        #pragma unroll
        for (int c = 0; c < 6; ++c) {
            lo[c] = min3f(r0[c], r1[c], r2[c]);
            mi[c] = med3f(r0[c], r1[c], r2[c]);
            hi[c] = max3f(r0[c], r1[c], r2[c]);
        }

        float4 o;
        o.x = med3f(max3f(lo[0], lo[1], lo[2]), med3f(mi[0], mi[1], mi[2]), min3f(hi[0], hi[1], hi[2]));
        o.y = med3f(max3f(lo[1], lo[2], lo[3]), med3f(mi[1], mi[2], mi[3]), min3f(hi[1], hi[2], hi[3]));
        o.z = med3f(max3f(lo[2], lo[3], lo[4]), med3f(mi[2], mi[3], mi[4]), min3f(hi[2], hi[3], hi[4]));
        o.w = med3f(max3f(lo[3], lo[4], lo[5]), med3f(mi[3], mi[4], mi[5]), min3f(hi[3], hi[4], hi[5]));

        // quantize the median (monotone f commutes with order statistics)
        o.x = truncf(o.x * scale) * rinv;
        o.y = truncf(o.y * scale) * rinv;
        o.z = truncf(o.z * scale) * rinv;
        o.w = truncf(o.w * scale) * rinv;
        *(float4*)(ob + (size_t)(y0 + i) * W + c0) = o;            // global_store_dwordx4

        #pragma unroll
        for (int c = 0; c < 6; ++c) { r0[c] = r1[c]; r1[c] = r2[c]; }  // renamed by unroll
    }
}

extern "C" void kernel_launch(void* const* d_in, const int* in_sizes, int n_in,
                              void* d_out, int out_size, void* d_ws, size_t ws_size,
                              hipStream_t stream) {
    const float* x  = (const float*)d_in[0];
    const int*   bd = (const int*)d_in[1];
    float*       out = (float*)d_out;

    const int B = in_sizes[0] / (H * W);   // 16
    dim3 grid(H / TY, B);                  // (128, 16)
    fsq_kernel<<<grid, 256, 0, stream>>>(x, bd, out);
}

// Round 8
// 111.667 us; speedup vs baseline: 1.0731x; 1.0047x over previous
//
#include <hip/hip_runtime.h>
#include <math.h>

// FeatureSqueezer: quantize trunc(x*scale)/scale + 3x3 median, reflect pad=1.
// x: (16, 1024, 1024) fp32. HBM floor: 128 MB -> ~21 us @ 6.3 TB/s (copy mix).
//
// Round-8 = round-7 with the compile fix: __builtin_nontemporal_store needs a
// clang ext_vector_type, not HIP's float4 class. Everything else unchanged:
//  - TY=4 strip, full 6-row raw batch prefetch (max MLP, ~80 VGPR -> ~6 waves/SIMD)
//  - median BEFORE quantize (monotone trunc(x*s)/s commutes with order stats)
//  - column triples via v_min3/v_med3/v_max3; merge:
//      med9 = med3( max3(lows), med3(mids), min3(highs) )
//  - horizontal halo via in-wave shuffle; wave-edge lanes fetch one
//    exec-masked dword per row (reflect folded into address math)
//  - nontemporal output stores (write-once stream, keep L2 for halo rows)

constexpr int H = 1024;
constexpr int W = 1024;
constexpr int TY = 4;            // output rows per block
constexpr int NR = TY + 2;       // prefetched rows

typedef float v4f __attribute__((ext_vector_type(4)));

__device__ __forceinline__ float min3f(float a, float b, float c) { return fminf(a, fminf(b, c)); }
__device__ __forceinline__ float max3f(float a, float b, float c) { return fmaxf(a, fmaxf(b, c)); }
__device__ __forceinline__ float med3f(float a, float b, float c) { return __builtin_amdgcn_fmed3f(a, b, c); }

__global__ __launch_bounds__(256) void fsq_kernel(const float* __restrict__ x,
                                                  const int* __restrict__ bdp,
                                                  float* __restrict__ out) {
    const int t    = threadIdx.x;          // 0..255 -> output cols 4t..4t+3
    const int lane = t & 63;
    const int y0   = blockIdx.x * TY;
    const int b    = blockIdx.y;

    const float q     = (float)((1 << bdp[0]) - 1);
    const float scale = 255.0f / q;
    const float rinv  = q / 255.0f;        // ~1/scale; quant error << 1.98e-2 threshold

    const size_t base = (size_t)b * H * W;
    const float* __restrict__ xb = x + base;
    float* __restrict__ ob       = out + base;

    const int c0 = 4 * t;
    // halo column wave-edge lanes fetch themselves (reflect folded in):
    const int cEdge = (lane == 0) ? ((c0 == 0) ? 1 : c0 - 1)
                                  : ((c0 + 4 < W) ? c0 + 4 : W - 2);
    const bool isEdge = (lane == 0) | (lane == 63);

    // ---- phase 1: issue ALL loads (raw values), maximal MLP ----
    v4f   m[NR];
    float e[NR];
    #pragma unroll
    for (int r = 0; r < NR; ++r) {
        int gy = y0 - 1 + r;
        gy = (gy < 0) ? 1 : ((gy >= H) ? 2 * H - 2 - gy : gy);     // reflect pad=1
        const float* row = xb + (size_t)gy * W;
        m[r] = *(const v4f*)(row + c0);                            // global_load_dwordx4
        e[r] = 0.0f;
        if (isEdge) e[r] = row[cEdge];                             // exec-masked dword
    }

    // ---- phase 2: shuffle raw halos, rolling 3-row median, quantize last ----
    float r0[6], r1[6], r2[6];

    auto mkrow = [&](int r, float* vv) {
        float l  = __shfl_up(m[r].w, 1, 64);                       // lane-1's col 4t-1
        float rr = __shfl_down(m[r].x, 1, 64);                     // lane+1's col 4t+4
        if (lane == 0)  l  = e[r];
        if (lane == 63) rr = e[r];
        vv[0] = l; vv[1] = m[r].x; vv[2] = m[r].y; vv[3] = m[r].z; vv[4] = m[r].w; vv[5] = rr;
    };

    mkrow(0, r0);
    mkrow(1, r1);

    #pragma unroll
    for (int i = 0; i < TY; ++i) {
        mkrow(2 + i, r2);

        // sort 6 vertical triples: (v_min3, v_med3, v_max3) on RAW values
        float lo[6], mi[6], hi[6];
        #pragma unroll
        for (int c = 0; c < 6; ++c) {
            lo[c] = min3f(r0[c], r1[c], r2[c]);
            mi[c] = med3f(r0[c], r1[c], r2[c]);
            hi[c] = max3f(r0[c], r1[c], r2[c]);
        }

        v4f o;
        o.x = med3f(max3f(lo[0], lo[1], lo[2]), med3f(mi[0], mi[1], mi[2]), min3f(hi[0], hi[1], hi[2]));
        o.y = med3f(max3f(lo[1], lo[2], lo[3]), med3f(mi[1], mi[2], mi[3]), min3f(hi[1], hi[2], hi[3]));
        o.z = med3f(max3f(lo[2], lo[3], lo[4]), med3f(mi[2], mi[3], mi[4]), min3f(hi[2], hi[3], hi[4]));
        o.w = med3f(max3f(lo[3], lo[4], lo[5]), med3f(mi[3], mi[4], mi[5]), min3f(hi[3], hi[4], hi[5]));

        // quantize the median (monotone f commutes with order statistics)
        o.x = truncf(o.x * scale) * rinv;
        o.y = truncf(o.y * scale) * rinv;
        o.z = truncf(o.z * scale) * rinv;
        o.w = truncf(o.w * scale) * rinv;
        __builtin_nontemporal_store(o, (v4f*)(ob + (size_t)(y0 + i) * W + c0));

        #pragma unroll
        for (int c = 0; c < 6; ++c) { r0[c] = r1[c]; r1[c] = r2[c]; }  // renamed by unroll
    }
}

extern "C" void kernel_launch(void* const* d_in, const int* in_sizes, int n_in,
                              void* d_out, int out_size, void* d_ws, size_t ws_size,
                              hipStream_t stream) {
    const float* x  = (const float*)d_in[0];
    const int*   bd = (const int*)d_in[1];
    float*       out = (float*)d_out;

    const int B = in_sizes[0] / (H * W);   // 16
    dim3 grid(H / TY, B);                  // (256, 16)
    fsq_kernel<<<grid, 256, 0, stream>>>(x, bd, out);
}